// Round 2
// baseline (854.333 us; speedup 1.0000x reference)
//
#include <hip/hip_runtime.h>
#include <cmath>

// Problem constants (from reference)
#define NB 4
#define NP 8192          // 2^13 points per batch
#define NE 262144        // 2^18 edges per batch
#define NTOT (NB * NE)   // 2^20 edges total
#define NDST (NB * NP)   // 32768 destination rows
#define NCIN 32
#define NCOUT 32
#define NH 16
#define GAMMA 4.0f

typedef _Float16 half8 __attribute__((ext_vector_type(8)));
typedef float floatx4 __attribute__((ext_vector_type(4)));

// ---------------------------------------------------------------------------
// Pipeline: counting-sort edges by global dst, then MFMA gather over sorted
// records. Kills the random-scatter atomic RMW traffic (was ~400 MB HBM).
//
// ws layout:
//   [0,       128K)   hist   (32768 u32)  -- zeroed each call
//   [128K,    256K)   cursor (32768 u32)  -- zeroed each call (scan writes it)
//   [256K, 256K+16M)  recs   (2^20 x float4 {srcg, dstg, r, pad})
// ---------------------------------------------------------------------------

__global__ void k_hist(const int* __restrict__ edge_dst, unsigned* __restrict__ hist) {
    const int stride = gridDim.x * blockDim.x;
    for (int i = blockIdx.x * blockDim.x + threadIdx.x; i < NTOT; i += stride) {
        const int b = i >> 18;                     // NE = 2^18
        const int dg = (b << 13) + edge_dst[i];    // NP = 2^13
        atomicAdd(&hist[dg], 1u);
    }
}

// single block, 1024 threads: exclusive scan of 32768 bins -> cursor
__global__ __launch_bounds__(1024)
void k_scan(const unsigned* __restrict__ hist, unsigned* __restrict__ cursor) {
    __shared__ unsigned sums[1024];
    const int t = threadIdx.x;
    unsigned local[32];
    unsigned s = 0;
    #pragma unroll
    for (int j = 0; j < 32; ++j) { local[j] = hist[t * 32 + j]; s += local[j]; }
    sums[t] = s;
    __syncthreads();
    // Hillis-Steele inclusive scan over 1024 thread-sums
    for (int off = 1; off < 1024; off <<= 1) {
        unsigned v = (t >= off) ? sums[t - off] : 0u;
        __syncthreads();
        sums[t] += v;
        __syncthreads();
    }
    unsigned run = (t == 0) ? 0u : sums[t - 1];
    #pragma unroll
    for (int j = 0; j < 32; ++j) { cursor[t * 32 + j] = run; run += local[j]; }
}

__global__ void k_scatter(const int* __restrict__ edge_src,
                          const int* __restrict__ edge_dst,
                          const float* __restrict__ edge_vec,
                          unsigned* __restrict__ cursor,
                          float4* __restrict__ recs) {
    const int stride = gridDim.x * blockDim.x;
    for (int i = blockIdx.x * blockDim.x + threadIdx.x; i < NTOT; i += stride) {
        const int b  = i >> 18;
        const int dg = (b << 13) + edge_dst[i];
        const int sg = (b << 13) + edge_src[i];
        const float vx = edge_vec[3 * i + 0];
        const float vy = edge_vec[3 * i + 1];
        const float vz = edge_vec[3 * i + 2];
        // ref's self-interaction zeroing (r<1e-10 -> vec=0) is a numeric no-op
        const float r = sqrtf(vx * vx + vy * vy + vz * vz);
        const unsigned pos = atomicAdd(&cursor[dg], 1u);
        float4 rec;
        rec.x = __int_as_float(sg);
        rec.y = __int_as_float(dg);
        rec.z = r;
        rec.w = 0.f;
        recs[pos] = rec;
    }
}

// GEMM view: msg[e, o] = sum_k Z[e,k] * W2T[k,o],  k = h*32 + i, K = 512
//   Z[e, h*32+i] = rbf_h(e) * x_src[e][i]
// MFMA f32_16x16x32_f16 layouts (HW-verified, learn_hip m89/m91):
//   A: lane holds A[m=lane&15][k_local = (lane>>4)*8 + j], j=0..7
//   B: lane holds B[k_local = (lane>>4)*8 + j][n = lane&15]
//   D: lane holds D[row=(lane>>4)*4 + r][col = lane&15], r=0..3
// k = s*32 + q*8 + j  =>  h = s, i = q*8+j: A-frag built directly in regs as
// rbf_s(edge m) * x_src[m][q*8..q*8+7].
__global__ __launch_bounds__(256, 4)
void k_main(const float* __restrict__ features,
            const float* __restrict__ W,
            const float* __restrict__ mu,
            const float4* __restrict__ recs,
            const int* __restrict__ n_norm_p,
            float* __restrict__ out)
{
    // W swizzled to exact B-fragment order (conflict-free b128 reads):
    //   wsw[ ((s*2+u)*64 + lane)*8 + j ] = W[h=s][o=(lane&15)+16u][i=(lane>>4)*8+j]
    __shared__ _Float16 wsw[16 * 2 * 64 * 8];   // 32 KiB
    __shared__ float mus[16];

    const int tid = threadIdx.x;
    for (int idx = tid; idx < 16384; idx += 256) {
        int j = idx & 7;
        int l = (idx >> 3) & 63;
        int u = (idx >> 9) & 1;
        int s = idx >> 10;
        int n = (l & 15) + (u << 4);
        int i = ((l >> 4) << 3) | j;
        wsw[idx] = (_Float16)W[(s * NCOUT + n) * NCIN + i];
    }
    if (tid < 16) mus[tid] = mu[tid];
    __syncthreads();

    const int lane = tid & 63;
    const int wv   = tid >> 6;
    const int m    = lane & 15;
    const int q    = lane >> 4;

    const int nn = n_norm_p[0];
    const float scale = (nn > 0) ? rsqrtf((float)nn) : 1.0f;

    // contiguous tile chunk per block: preserves sorted-dst locality per XCD
    const int tiles_per_block = 16384 / gridDim.x;   // grid=1024 -> 16
    const long t0 = (long)blockIdx.x * tiles_per_block;

    for (int ti = 0; ti < tiles_per_block; ++ti) {
        const long ebase = (t0 + ti) * 64 + (long)wv * 16;

        const float4 rc = recs[ebase + m];
        const int   sg = __float_as_int(rc.x);
        const int   dg = __float_as_int(rc.y);
        const float r  = rc.z;

        const float* xrow = features + (long)sg * NCIN + q * 8;
        floatx4 xa = *(const floatx4*)(xrow);
        floatx4 xb = *(const floatx4*)(xrow + 4);

        float rbf[16];
        #pragma unroll
        for (int s = 0; s < 16; ++s) {
            float d = r - mus[s];
            rbf[s] = __expf(-GAMMA * d * d);
        }

        floatx4 accLo = {0.f, 0.f, 0.f, 0.f};
        floatx4 accHi = {0.f, 0.f, 0.f, 0.f};

        #pragma unroll
        for (int s = 0; s < 16; ++s) {
            const float rb = rbf[s];
            half8 a;
            a[0] = (_Float16)(rb * xa[0]);
            a[1] = (_Float16)(rb * xa[1]);
            a[2] = (_Float16)(rb * xa[2]);
            a[3] = (_Float16)(rb * xa[3]);
            a[4] = (_Float16)(rb * xb[0]);
            a[5] = (_Float16)(rb * xb[1]);
            a[6] = (_Float16)(rb * xb[2]);
            a[7] = (_Float16)(rb * xb[3]);
            half8 b0 = *(const half8*)(wsw + ((s * 2 + 0) * 64 + lane) * 8);
            half8 b1 = *(const half8*)(wsw + ((s * 2 + 1) * 64 + lane) * 8);
            accLo = __builtin_amdgcn_mfma_f32_16x16x32_f16(a, b0, accLo, 0, 0, 0);
            accHi = __builtin_amdgcn_mfma_f32_16x16x32_f16(a, b1, accHi, 0, 0, 0);
        }

        // Epilogue: lane holds D[row=q*4+rr][col=m]; row's dstg lives in lane
        // (q*4+rr) of this wave (its m == q*4+rr, q==0 copy). Sorted order =>
        // most rows in a tile share dstg => atomics hit hot L2 lines.
        #pragma unroll
        for (int rr = 0; rr < 4; ++rr) {
            const int dgr = __shfl(dg, q * 4 + rr, 64);
            float* orow = out + (long)dgr * NCOUT;
            atomicAdd(orow + m,      accLo[rr] * scale);
            atomicAdd(orow + m + 16, accHi[rr] * scale);
        }
    }
}

extern "C" void kernel_launch(void* const* d_in, const int* in_sizes, int n_in,
                              void* d_out, int out_size, void* d_ws, size_t ws_size,
                              hipStream_t stream) {
    const float* features = (const float*)d_in[0];
    const float* edge_vec = (const float*)d_in[1];
    const float* W        = (const float*)d_in[2];
    const float* mu       = (const float*)d_in[3];
    const int*   edge_src = (const int*)d_in[4];
    const int*   edge_dst = (const int*)d_in[5];
    const int*   n_norm   = (const int*)d_in[6];
    float* out = (float*)d_out;

    unsigned* hist   = (unsigned*)d_ws;
    unsigned* cursor = hist + NDST;
    float4*   recs   = (float4*)((char*)d_ws + 256 * 1024);

    // zero hist (cursor is fully written by k_scan; out accumulated via atomics)
    hipMemsetAsync(hist, 0, NDST * sizeof(unsigned), stream);
    hipMemsetAsync(out, 0, (size_t)out_size * sizeof(float), stream);

    k_hist   <<<2048, 256, 0, stream>>>(edge_dst, hist);
    k_scan   <<<1, 1024, 0, stream>>>(hist, cursor);
    k_scatter<<<2048, 256, 0, stream>>>(edge_src, edge_dst, edge_vec, cursor, recs);
    k_main   <<<1024, 256, 0, stream>>>(features, W, mu, recs, n_norm, out);
}

// Round 3
// 304.370 us; speedup vs baseline: 2.8069x; 2.8069x over previous
//
#include <hip/hip_runtime.h>
#include <cmath>

// Problem constants (from reference)
#define NB 4
#define NP 8192          // 2^13 points per batch
#define NE 262144        // 2^18 edges per batch
#define NTOT (NB * NE)   // 2^20 edges total
#define NCIN 32
#define NCOUT 32
#define NH 16
#define GAMMA 4.0f

#define BINS 2048        // dst-tile bins: bin = dg>>4 (16 dst rows per bin)
#define CAP  1024        // bucket capacity (lambda=512, 1024 = +23 sigma; overflow ~impossible)

typedef _Float16 half8 __attribute__((ext_vector_type(8)));
typedef float floatx4 __attribute__((ext_vector_type(4)));

// ---------------------------------------------------------------------------
// Factorized algorithm (16x fewer FLOPs than per-edge K(r)@x):
//   G[d, k(h,i)] = sum_{e: dst=d} rbf_h(r_e) * x[src_e, i]     (rank-1 per edge)
//   out[d, o]    = sum_k G[d,k] * Wf[k,o]                      (16x512x32 MFMA per 16-row tile)
// Zero atomics on out; ~453K global atomics total (bucket reservation only).
//
// ws layout: gcnt[2048] u32 @0 ; recs (u64) @8192, 2048*1024*8 = 16 MB
// rec = { bits 0..15: srcg, bits 16..19: row (dg&15), bits 32..63: r (f32) }
// ---------------------------------------------------------------------------

__global__ __launch_bounds__(256)
void k_scatter(const int* __restrict__ edge_src,
               const int* __restrict__ edge_dst,
               const float* __restrict__ edge_vec,
               unsigned* __restrict__ gcnt,
               unsigned long long* __restrict__ recs)
{
    __shared__ unsigned lh[BINS];    // local hist, then absolute cursors
    const int t = threadIdx.x;
    const long e0 = (long)blockIdx.x * 4096;    // 256 blocks x 4096 edges

    for (int b = t; b < BINS; b += 256) lh[b] = 0;
    __syncthreads();

    int dgs[16];
    #pragma unroll
    for (int j = 0; j < 16; ++j) {
        const long e = e0 + j * 256 + t;
        const int bb = (int)(e >> 18);
        const int dg = (bb << 13) + edge_dst[e];
        dgs[j] = dg;
        atomicAdd(&lh[dg >> 4], 1u);
    }
    __syncthreads();

    // one global atomic per nonzero bin per block (~1771 of 2048)
    for (int b = t; b < BINS; b += 256) {
        const unsigned c = lh[b];
        unsigned base = 0;
        if (c) base = atomicAdd(&gcnt[b], c);
        lh[b] = (unsigned)b * CAP + base;       // absolute cursor
    }
    __syncthreads();

    #pragma unroll
    for (int j = 0; j < 16; ++j) {
        const long e = e0 + j * 256 + t;
        const int dg = dgs[j];
        const int bin = dg >> 4;
        const int bb = (int)(e >> 18);
        const int sg = (bb << 13) + edge_src[e];
        const float vx = edge_vec[3 * e + 0];
        const float vy = edge_vec[3 * e + 1];
        const float vz = edge_vec[3 * e + 2];
        // ref's self-interaction zeroing (r<1e-10 -> vec=0) is a numeric no-op
        const float r = sqrtf(vx * vx + vy * vy + vz * vz);
        const unsigned slot = atomicAdd(&lh[bin], 1u);
        if (slot < (unsigned)bin * CAP + CAP) {
            const unsigned lo = (unsigned)sg | ((unsigned)(dg & 15) << 16);
            recs[slot] = ((unsigned long long)__float_as_uint(r) << 32) | lo;
        }
    }
}

// One block per bin (16 dst rows). LDS ~50.4 KB -> 3 blocks/CU.
__global__ __launch_bounds__(256)
void k_fused(const float* __restrict__ features,
             const float* __restrict__ Wg,
             const float* __restrict__ mu_g,
             const unsigned* __restrict__ gcnt,
             const unsigned long long* __restrict__ recs,
             const int* __restrict__ n_norm_p,
             float* __restrict__ out)
{
    __shared__ unsigned long long raw[CAP];    // 8 KB (reused as pacc in epilogue)
    __shared__ unsigned long long srt[CAP];    // 8 KB row-sorted records
    __shared__ float G[64 * 132];              // 33.8 KB; G[(h*4+q)*132 + row*8 + j]
    __shared__ unsigned h16[16], o16[16];

    const int t    = threadIdx.x;
    const int lane = t & 63;
    const int wv   = t >> 6;
    const int bin  = blockIdx.x;               // 2048 bins

    int n = (int)gcnt[bin];
    if (n > CAP) n = CAP;

    // load bucket records + zero G
    for (int i = t; i < n; i += 256) raw[i] = recs[(long)bin * CAP + i];
    for (int i = t; i < 64 * 132; i += 256) G[i] = 0.f;
    if (t < 16) h16[t] = 0;
    __syncthreads();

    // LDS counting-sort by row (4-bit)
    for (int i = t; i < n; i += 256) atomicAdd(&h16[(unsigned)(raw[i] >> 16) & 15u], 1u);
    __syncthreads();
    if (t == 0) {
        unsigned run = 0;
        for (int b = 0; b < 16; ++b) { o16[b] = run; run += h16[b]; }
    }
    __syncthreads();
    if (t < 16) h16[t] = o16[t];               // cursors
    __syncthreads();
    for (int i = t; i < n; i += 256) {
        const unsigned long long rc = raw[i];
        const unsigned slot = atomicAdd(&h16[(unsigned)(rc >> 16) & 15u], 1u);
        srt[slot] = rc;
    }
    __syncthreads();

    // ---- stage 1: G accumulation ----
    // lane owns k-set {h = lane>>2, i = (lane&3)*8 + 0..7}; each wave covers the
    // FULL k-range over a contiguous quarter of the (row-sorted) edge list.
    // Row-runs accumulate in registers; ds_add_f32 flush at row transitions.
    const int h  = lane >> 2;
    const int qq = lane & 3;
    const float muh = mu_g[h];

    const int e0w = (n * wv) >> 2;
    const int e1w = (n * (wv + 1)) >> 2;

    float acc[8];
    #pragma unroll
    for (int j = 0; j < 8; ++j) acc[j] = 0.f;
    int prow = -1;
    float* Gme = &G[(h * 4 + qq) * 132];

    if (e0w < e1w) {
        unsigned long long rc = srt[e0w];
        {
            const int sg = (int)(rc & 0xFFFFu);
            const floatx4* xp = (const floatx4*)(features + ((long)sg << 5) + qq * 8);
            floatx4 x0 = xp[0], x1 = xp[1];
            for (int e = e0w; e < e1w; ++e) {
                // 1-deep software pipeline: next rec + next x issued before FMAs
                const int en = (e + 1 < e1w) ? e + 1 : e;
                const unsigned long long rcn = srt[en];
                const int sgn = (int)(rcn & 0xFFFFu);
                const floatx4* xpn = (const floatx4*)(features + ((long)sgn << 5) + qq * 8);
                const floatx4 x0n = xpn[0], x1n = xpn[1];

                const int row = (int)((rc >> 16) & 15u);
                if (row != prow) {                        // wave-uniform branch
                    if (prow >= 0) {
                        float* gp = Gme + prow * 8;
                        #pragma unroll
                        for (int j = 0; j < 8; ++j) { atomicAdd(&gp[j], acc[j]); acc[j] = 0.f; }
                    }
                    prow = row;
                }
                const float r = __uint_as_float((unsigned)(rc >> 32));
                const float d = r - muh;
                const float rb = __expf(-GAMMA * d * d);
                acc[0] += rb * x0[0]; acc[1] += rb * x0[1];
                acc[2] += rb * x0[2]; acc[3] += rb * x0[3];
                acc[4] += rb * x1[0]; acc[5] += rb * x1[1];
                acc[6] += rb * x1[2]; acc[7] += rb * x1[3];

                rc = rcn; x0 = x0n; x1 = x1n;
            }
            float* gp = Gme + prow * 8;
            #pragma unroll
            for (int j = 0; j < 8; ++j) atomicAdd(&gp[j], acc[j]);
        }
    }
    __syncthreads();

    // ---- stage 2: out[16 rows][32 ch] = G (16x512) @ Wf (512x32), MFMA f16 ----
    // wave wv covers s in [4wv, 4wv+4); partial C reduced through LDS.
    const int m = lane & 15;
    const int q = lane >> 4;
    const int nn = n_norm_p[0];
    const float scale = (nn > 0) ? rsqrtf((float)nn) : 1.0f;

    floatx4 accLo = {0.f, 0.f, 0.f, 0.f};
    floatx4 accHi = {0.f, 0.f, 0.f, 0.f};
    for (int s = wv * 4; s < wv * 4 + 4; ++s) {
        const floatx4* gp = (const floatx4*)&G[(s * 4 + q) * 132 + m * 8];
        const floatx4 ga = gp[0], gb = gp[1];
        half8 a;
        a[0] = (_Float16)ga[0]; a[1] = (_Float16)ga[1];
        a[2] = (_Float16)ga[2]; a[3] = (_Float16)ga[3];
        a[4] = (_Float16)gb[0]; a[5] = (_Float16)gb[1];
        a[6] = (_Float16)gb[2]; a[7] = (_Float16)gb[3];
        // B-frag: lane holds Wf[s*32+q*8+j][o] = W[s][o][q*8+j], o = m (+16)
        const floatx4* wp0 = (const floatx4*)(Wg + ((long)(s * 32 + m) * 32 + q * 8));
        const floatx4 w00 = wp0[0], w01 = wp0[1];
        const floatx4* wp1 = (const floatx4*)(Wg + ((long)(s * 32 + m + 16) * 32 + q * 8));
        const floatx4 w10 = wp1[0], w11 = wp1[1];
        half8 b0, b1;
        b0[0] = (_Float16)w00[0]; b0[1] = (_Float16)w00[1];
        b0[2] = (_Float16)w00[2]; b0[3] = (_Float16)w00[3];
        b0[4] = (_Float16)w01[0]; b0[5] = (_Float16)w01[1];
        b0[6] = (_Float16)w01[2]; b0[7] = (_Float16)w01[3];
        b1[0] = (_Float16)w10[0]; b1[1] = (_Float16)w10[1];
        b1[2] = (_Float16)w10[2]; b1[3] = (_Float16)w10[3];
        b1[4] = (_Float16)w11[0]; b1[5] = (_Float16)w11[1];
        b1[6] = (_Float16)w11[2]; b1[7] = (_Float16)w11[3];
        accLo = __builtin_amdgcn_mfma_f32_16x16x32_f16(a, b0, accLo, 0, 0, 0);
        accHi = __builtin_amdgcn_mfma_f32_16x16x32_f16(a, b1, accHi, 0, 0, 0);
    }

    // reduce 4 partial C's (reuse raw as pacc)
    float* pacc = (float*)raw;
    floatx4* pp = (floatx4*)&pacc[(wv * 64 + lane) * 8];
    pp[0] = accLo; pp[1] = accHi;
    __syncthreads();
    if (wv == 0) {
        floatx4 lo = {0.f, 0.f, 0.f, 0.f}, hi = {0.f, 0.f, 0.f, 0.f};
        #pragma unroll
        for (int w = 0; w < 4; ++w) {
            const floatx4* qp = (const floatx4*)&pacc[(w * 64 + lane) * 8];
            lo += qp[0]; hi += qp[1];
        }
        const int d0 = bin * 16;
        #pragma unroll
        for (int rr = 0; rr < 4; ++rr) {
            float* orow = out + (long)(d0 + q * 4 + rr) * NCOUT;
            orow[m]      = lo[rr] * scale;    // D[row=q*4+rr][col=m], plain store
            orow[m + 16] = hi[rr] * scale;
        }
    }
}

extern "C" void kernel_launch(void* const* d_in, const int* in_sizes, int n_in,
                              void* d_out, int out_size, void* d_ws, size_t ws_size,
                              hipStream_t stream) {
    const float* features = (const float*)d_in[0];
    const float* edge_vec = (const float*)d_in[1];
    const float* W        = (const float*)d_in[2];
    const float* mu       = (const float*)d_in[3];
    const int*   edge_src = (const int*)d_in[4];
    const int*   edge_dst = (const int*)d_in[5];
    const int*   n_norm   = (const int*)d_in[6];
    float* out = (float*)d_out;

    unsigned* gcnt = (unsigned*)d_ws;
    unsigned long long* recs = (unsigned long long*)((char*)d_ws + 8192);

    hipMemsetAsync(gcnt, 0, BINS * sizeof(unsigned), stream);
    k_scatter<<<256, 256, 0, stream>>>(edge_src, edge_dst, edge_vec, gcnt, recs);
    k_fused<<<BINS, 256, 0, stream>>>(features, W, mu, gcnt, recs, n_norm, out);
}